// Round 6
// baseline (732.176 us; speedup 1.0000x reference)
//
#include <hip/hip_runtime.h>
#include <hip/hip_bf16.h>

// Mamba2 fused block, MI355X. Round 6: Y_off factored out as batched MFMA GEMM
// (C shared across heads, ea[l] row-scale epilogue); scores via same MFMA kernel;
// ydiag diag-only with double-buffered single-barrier K-loop + RMW-add epilogue.

#define LL 4096
#define DPROJ 4384
#define CONVD 2304
#define DIN 2048
#define NH 32
#define HD 64
#define DS 128
#define CH 256
#define NC 16

typedef unsigned short u16;
typedef unsigned int u32;
typedef __attribute__((ext_vector_type(8))) short bf16x8;
typedef __attribute__((ext_vector_type(4))) float f32x4;

__device__ __forceinline__ float bf2f(u16 v) {
    u32 x = ((u32)v) << 16;
    float f; __builtin_memcpy(&f, &x, 4); return f;
}
__device__ __forceinline__ u16 f2bf(float f) {
    u32 x; __builtin_memcpy(&x, &f, 4);
    u32 r = (x + 0x7fffu + ((x >> 16) & 1u)) >> 16;   // RNE
    return (u16)r;
}
__device__ __forceinline__ float ldin(const void* p, size_t i, int bf) {
    if (bf) return bf2f(((const u16*)p)[i]);
    return ((const float*)p)[i];
}
__device__ __forceinline__ void stout(void* p, size_t i, int bf, float v) {
    if (bf) ((u16*)p)[i] = f2bf(v);
    else    ((float*)p)[i] = v;
}
__device__ __forceinline__ void gll16(const u16* g, u16* l) {
    __builtin_amdgcn_global_load_lds((const u32*)g, (u32*)l, 16, 0, 0);
}

// ---------------- dtype detector ----------------
__global__ void k_detect(const void* u, int* flag) {
    __shared__ int cnt;
    if (threadIdx.x == 0) cnt = 0;
    __syncthreads();
    u16 bits = ((const u16*)u)[2 * threadIdx.x];
    int e = (bits >> 7) & 0xff;
    int ok = (e >= 100 && e <= 141) ? 1 : 0;
    atomicAdd(&cnt, ok);
    __syncthreads();
    if (threadIdx.x == 0) *flag = (cnt > 128) ? 1 : 0;
}

// ---------------- cast to bf16 (identity when input already bf16) ----------------
__global__ void k_cast(const void* src, u16* dst, const int* flagp, int n4) {
    int fl = *flagp;
    size_t i = (size_t)blockIdx.x * 256 + threadIdx.x;
    if (i >= (size_t)n4) return;
    if (fl) {
        ((u32*)dst)[i * 2]     = ((const u32*)src)[i * 2];
        ((u32*)dst)[i * 2 + 1] = ((const u32*)src)[i * 2 + 1];
    } else {
        float4 v = ((const float4*)src)[i];
        dst[i * 4 + 0] = f2bf(v.x); dst[i * 4 + 1] = f2bf(v.y);
        dst[i * 4 + 2] = f2bf(v.z); dst[i * 4 + 3] = f2bf(v.w);
    }
}

// ---------------- transpose + cast: src[R][Cc] -> dst[Cpad][R] bf16, zero-fill ----------------
__global__ __launch_bounds__(256) void k_transpose(const void* src, u16* dst,
                                                   int R, int Cc, const int* flagp) {
    int fl = *flagp;
    __shared__ float tile[32][33];
    int r0 = blockIdx.y * 32, c0 = blockIdx.x * 32;
    int t = threadIdx.x;
    int tr = t >> 5, tc = t & 31;
#pragma unroll
    for (int i = 0; i < 4; ++i) {
        int r = r0 + tr + i * 8, c = c0 + tc;
        float v = 0.f;
        if (c < Cc) v = ldin(src, (size_t)r * Cc + c, fl);
        tile[tr + i * 8][tc] = v;
    }
    __syncthreads();
#pragma unroll
    for (int i = 0; i < 4; ++i) {
        int c = c0 + tr + i * 8, r = r0 + tc;
        dst[(size_t)c * R + r] = f2bf(tile[tc][tr + i * 8]);
    }
}

// ---------------- MFMA GEMM (row stride == K): C = A[M,K] @ Bt[N,K]^T ----------------
__global__ __launch_bounds__(256) void k_gemm_bt(const u16* __restrict__ A, const u16* __restrict__ Bt,
                                                 int K, int mode,
                                                 u16* o0, u16* o1, u16* o2,
                                                 void* outF, const int* flagp) {
    __shared__ __align__(16) u16 sA[4096];
    __shared__ __align__(16) u16 sB[4096];
    int t = threadIdx.x;
    int lane = t & 63, w = t >> 6;
    int wr = w >> 1, wc = w & 1;
    int m0 = blockIdx.y * 128, n0 = blockIdx.x * 128;

    const u16* gA[2]; const u16* gB[2];
    u16* lA[2]; u16* lB[2];
#pragma unroll
    for (int r = 0; r < 2; ++r) {
        int c = w * 128 + r * 64 + lane;
        int m = c >> 2;
        int ks = (c & 3) ^ ((m >> 1) & 3);
        gA[r] = A + (size_t)(m0 + m) * K + ks * 8;
        gB[r] = Bt + (size_t)(n0 + m) * K + ks * 8;
        lA[r] = sA + (size_t)(w * 128 + r * 64) * 8;
        lB[r] = sB + (size_t)(w * 128 + r * 64) * 8;
    }
    int q = lane >> 4, l15 = lane & 15;
    int offA[4], offB[4];
#pragma unroll
    for (int i = 0; i < 4; ++i) {
        int m = wr * 64 + i * 16 + l15;
        offA[i] = (m * 4 + (q ^ ((m >> 1) & 3))) * 8;
        int n = wc * 64 + i * 16 + l15;
        offB[i] = (n * 4 + (q ^ ((n >> 1) & 3))) * 8;
    }
    f32x4 acc[4][4];
#pragma unroll
    for (int i = 0; i < 4; ++i)
#pragma unroll
        for (int j = 0; j < 4; ++j) acc[i][j] = (f32x4){0.f, 0.f, 0.f, 0.f};

    for (int k0 = 0; k0 < K; k0 += 32) {
        gll16(gA[0] + k0, lA[0]);
        gll16(gA[1] + k0, lA[1]);
        gll16(gB[0] + k0, lB[0]);
        gll16(gB[1] + k0, lB[1]);
        __syncthreads();
        bf16x8 af[4], bfv[4];
#pragma unroll
        for (int i = 0; i < 4; ++i) af[i] = *(const bf16x8*)(sA + offA[i]);
#pragma unroll
        for (int i = 0; i < 4; ++i) bfv[i] = *(const bf16x8*)(sB + offB[i]);
#pragma unroll
        for (int i = 0; i < 4; ++i)
#pragma unroll
            for (int j = 0; j < 4; ++j)
                acc[i][j] = __builtin_amdgcn_mfma_f32_16x16x32_bf16(af[i], bfv[j], acc[i][j], 0, 0, 0);
        __syncthreads();
    }

    int fl = (mode == 1) ? *flagp : 0;
#pragma unroll
    for (int i = 0; i < 4; ++i) {
#pragma unroll
        for (int j = 0; j < 4; ++j) {
            int mrow = m0 + wr * 64 + i * 16 + q * 4;
            int n = n0 + wc * 64 + j * 16 + l15;
#pragma unroll
            for (int r = 0; r < 4; ++r) {
                float v = acc[i][j][r];
                size_t m = (size_t)(mrow + r);
                if (mode == 0) {
                    if (n < DIN) o0[m * DIN + n] = f2bf(v);
                    else if (n < DIN + CONVD) o1[m * CONVD + (n - DIN)] = f2bf(v);
                    else if (n < DPROJ) o2[m * NH + (n - DIN - CONVD)] = f2bf(v);
                } else {
                    stout(outF, m * 1024 + n, fl, v);
                }
            }
        }
    }
}

// ---------------- strided MFMA GEMM, K=128, per-(b,c) batch ----------------
// mode 0: scores  G[bc][m][n] = C[m]·B[n]         (M=256, N=256)
// mode 1: Y_off   Yb[l][h*64+p] = ea[l]·C[l]·P_h  (M=256, N=2048, Bt=STt rows)
__global__ __launch_bounds__(256) void k_ssd_gemm(const u16* __restrict__ Abase,
                                                  const u16* __restrict__ Btbase,
                                                  int lda, int ldb, size_t strA, size_t strB,
                                                  int mode, u16* G, const float* ACS, u16* Yb) {
    int bc = blockIdx.z;
    const u16* A = Abase + strA * bc;
    const u16* Bt = Btbase + strB * bc;
    __shared__ __align__(16) u16 sA[4096];
    __shared__ __align__(16) u16 sB[4096];
    int t = threadIdx.x;
    int lane = t & 63, w = t >> 6;
    int wr = w >> 1, wc = w & 1;
    int m0 = blockIdx.y * 128, n0 = blockIdx.x * 128;

    const u16* gA[2]; const u16* gB[2];
    u16* lA[2]; u16* lB[2];
#pragma unroll
    for (int r = 0; r < 2; ++r) {
        int c = w * 128 + r * 64 + lane;
        int m = c >> 2;
        int ks = (c & 3) ^ ((m >> 1) & 3);
        gA[r] = A + (size_t)(m0 + m) * lda + ks * 8;
        gB[r] = Bt + (size_t)(n0 + m) * ldb + ks * 8;
        lA[r] = sA + (size_t)(w * 128 + r * 64) * 8;
        lB[r] = sB + (size_t)(w * 128 + r * 64) * 8;
    }
    int q = lane >> 4, l15 = lane & 15;
    int offA[4], offB[4];
#pragma unroll
    for (int i = 0; i < 4; ++i) {
        int m = wr * 64 + i * 16 + l15;
        offA[i] = (m * 4 + (q ^ ((m >> 1) & 3))) * 8;
        int n = wc * 64 + i * 16 + l15;
        offB[i] = (n * 4 + (q ^ ((n >> 1) & 3))) * 8;
    }
    f32x4 acc[4][4];
#pragma unroll
    for (int i = 0; i < 4; ++i)
#pragma unroll
        for (int j = 0; j < 4; ++j) acc[i][j] = (f32x4){0.f, 0.f, 0.f, 0.f};

    for (int k0 = 0; k0 < 128; k0 += 32) {
        gll16(gA[0] + k0, lA[0]);
        gll16(gA[1] + k0, lA[1]);
        gll16(gB[0] + k0, lB[0]);
        gll16(gB[1] + k0, lB[1]);
        __syncthreads();
        bf16x8 af[4], bfv[4];
#pragma unroll
        for (int i = 0; i < 4; ++i) af[i] = *(const bf16x8*)(sA + offA[i]);
#pragma unroll
        for (int i = 0; i < 4; ++i) bfv[i] = *(const bf16x8*)(sB + offB[i]);
#pragma unroll
        for (int i = 0; i < 4; ++i)
#pragma unroll
            for (int j = 0; j < 4; ++j)
                acc[i][j] = __builtin_amdgcn_mfma_f32_16x16x32_bf16(af[i], bfv[j], acc[i][j], 0, 0, 0);
        __syncthreads();
    }

    if (mode == 0) {
        size_t gb = (size_t)bc * 65536;
#pragma unroll
        for (int i = 0; i < 4; ++i) {
#pragma unroll
            for (int j = 0; j < 4; ++j) {
                int mrow = m0 + wr * 64 + i * 16 + q * 4;
                int n = n0 + wc * 64 + j * 16 + l15;
#pragma unroll
                for (int r = 0; r < 4; ++r)
                    G[gb + (size_t)(mrow + r) * 256 + n] = f2bf(acc[i][j][r]);
            }
        }
    } else {
        int b = bc >> 4, c = bc & 15;
        size_t bL = (size_t)b * LL + c * CH;
        int hq = (n0 >> 6) + wc;
        const float* ar = ACS + (size_t)(bc * 32 + hq) * 256;
        float eal[4][4];
#pragma unroll
        for (int i = 0; i < 4; ++i)
#pragma unroll
            for (int r = 0; r < 4; ++r)
                eal[i][r] = __expf(ar[m0 + wr * 64 + i * 16 + q * 4 + r]);
#pragma unroll
        for (int i = 0; i < 4; ++i) {
#pragma unroll
            for (int j = 0; j < 4; ++j) {
                int l = m0 + wr * 64 + i * 16 + q * 4;
                int p = j * 16 + l15;
#pragma unroll
                for (int r = 0; r < 4; ++r)
                    Yb[(bL + l + r) * (size_t)DIN + hq * 64 + p] = f2bf(acc[i][j][r] * eal[i][r]);
            }
        }
    }
}

// ---------------- dt softplus + per-chunk cumsum of dA ----------------
__global__ __launch_bounds__(256) void k_dtcum(const u16* DTraw, const void* dtb, const void* alog,
                                               const int* flagp, float* DT, float* ACS, float* AL) {
    int fl = *flagp;
    int bid = blockIdx.x;                 // (b*16+c)*32+h
    int b = bid >> 9, c = (bid >> 5) & 15, h = bid & 31;
    int t = threadIdx.x;
    size_t bl = (size_t)b * LL + c * CH + t;
    float v = bf2f(DTraw[bl * NH + h]) + ldin(dtb, h, fl);
    float sp = (v > 20.f) ? v : log1pf(__expf(v));
    DT[bl * NH + h] = sp;
    float da = -__expf(ldin(alog, h, fl)) * sp;
    __shared__ float sc[256];
    sc[t] = da;
    __syncthreads();
    for (int off = 1; off < 256; off <<= 1) {
        float add = (t >= off) ? sc[t - off] : 0.f;
        __syncthreads();
        sc[t] += add;
        __syncthreads();
    }
    ACS[(size_t)bid * CH + t] = sc[t];
    if (t == 255) AL[bid] = sc[255];
}

// ---------------- causal depthwise conv (width 4) + silu ----------------
__global__ void k_conv(const u16* XBCr, const void* cw, const void* cb, const int* flagp, u16* XCb) {
    int fl = *flagp;
    int ch = blockIdx.x * 256 + threadIdx.x;   // 0..2303 (grid.x = 9)
    size_t bl = blockIdx.y;                    // 0..8191
    int l = (int)(bl & 4095);
    float acc = ldin(cb, ch, fl);
#pragma unroll
    for (int j = 0; j < 4; ++j) {
        int ls = l + j - 3;
        if (ls >= 0)
            acc += bf2f(XBCr[(bl - l + ls) * CONVD + ch]) * ldin(cw, (size_t)ch * 4 + j, fl);
    }
    acc = acc / (1.f + __expf(-acc));
    XCb[bl * CONVD + ch] = f2bf(acc);
}

// ---------------- per-chunk states via MFMA: STt[p][n] = sum_l X[l,p]*wl[l] * B[l,n] ----------------
__global__ __launch_bounds__(256) void k_states(const u16* XCb, const float* DT, const float* ACS,
                                                const float* AL, u16* STt) {
    int bid = blockIdx.x;            // (b*16+c)*32+h
    int b = bid >> 9, c = (bid >> 5) & 15, h = bid & 31;
    int t = threadIdx.x;
    size_t bL = (size_t)b * LL + c * CH;
    __shared__ float wl[256];
    __shared__ __align__(16) u16 Wt[128 * 38];   // B^T: [n][lk]
    __shared__ __align__(16) u16 Pt[64 * 38];    // X^T*wl: [p][lk]
    float al = AL[bid];
    wl[t] = __expf(al - ACS[(size_t)bid * CH + t]) * DT[(bL + t) * NH + h];
    __syncthreads();

    int lane = t & 63, w = t >> 6;
    int q = lane >> 4, l15 = lane & 15;
    f32x4 acc[8];
#pragma unroll
    for (int j = 0; j < 8; ++j) acc[j] = (f32x4){0.f, 0.f, 0.f, 0.f};

    for (int kt = 0; kt < 8; ++kt) {
        int l0 = kt * 32;
        if (kt) __syncthreads();
#pragma unroll
        for (int e = 0; e < 16; ++e) {
            int i = e * 256 + t;
            int n = i & 127, lk = i >> 7;
            Wt[n * 38 + lk] = XCb[(bL + l0 + lk) * CONVD + DIN + n];
        }
#pragma unroll
        for (int e = 0; e < 8; ++e) {
            int i = e * 256 + t;
            int p = i & 63, lk = i >> 6;
            float v = bf2f(XCb[(bL + l0 + lk) * CONVD + h * HD + p]) * wl[l0 + lk];
            Pt[p * 38 + lk] = f2bf(v);
        }
        __syncthreads();
        bf16x8 af = *(const bf16x8*)&Pt[(w * 16 + l15) * 38 + q * 8];
#pragma unroll
        for (int j = 0; j < 8; ++j) {
            bf16x8 bv = *(const bf16x8*)&Wt[(j * 16 + l15) * 38 + q * 8];
            acc[j] = __builtin_amdgcn_mfma_f32_16x16x32_bf16(af, bv, acc[j], 0, 0, 0);
        }
    }
    size_t sbase = (size_t)bid * 8192;
#pragma unroll
    for (int j = 0; j < 8; ++j)
#pragma unroll
        for (int r = 0; r < 4; ++r)
            STt[sbase + (size_t)(w * 16 + q * 4 + r) * 128 + j * 16 + l15] = f2bf(acc[j][r]);
}

// ---------------- inter-chunk scan (in place; f32 carry; layout-agnostic) ----------------
__global__ __launch_bounds__(256) void k_scan(const float* AL, u16* ST) {
    int bid = blockIdx.x;  // b*32+h
    int b = bid >> 5, h = bid & 31;
    int t = threadIdx.x;
    float Pv[32];
#pragma unroll
    for (int k = 0; k < 32; ++k) Pv[k] = 0.f;
    for (int c = 0; c < NC; ++c) {
        int bch = (b * NC + c) * NH + h;
        float ga = __expf(AL[bch]);
        size_t base = (size_t)bch * 8192;
#pragma unroll
        for (int k = 0; k < 32; ++k) {
            size_t idx = base + (size_t)k * 256 + t;
            float s = bf2f(ST[idx]);
            ST[idx] = f2bf(Pv[k]);
            Pv[k] = ga * Pv[k] + s;
        }
    }
}

// ---------------- Y_diag via MFMA (diag-only, double-buffered, RMW add onto Y_off) ----------------
__global__ __launch_bounds__(256) void k_ydiag(const u16* XCb, const float* DT, const float* ACS,
                                               const u16* G, u16* Yb) {
    int bid = blockIdx.x >> 2;       // (b*16+c)*32+h
    int lt = blockIdx.x & 3;
    int b = bid >> 9, c = (bid >> 5) & 15, h = bid & 31;
    int t = threadIdx.x;
    int l0b = lt * 64;
    size_t bL = (size_t)b * LL + c * CH;
    size_t gbase = (size_t)(b * NC + c) * 65536;
    __shared__ float acs_s[256];
    __shared__ float dts_s[256];
    __shared__ float rowf[64];
    __shared__ float colf[192];
    __shared__ __align__(16) u16 Wt[2][2432];
    __shared__ __align__(16) u16 Pt[2][2432];

    acs_s[t] = ACS[(size_t)bid * CH + t];
    dts_s[t] = DT[(bL + t) * NH + h];
    __syncthreads();
    float aref = acs_s[l0b];
    if (t < 64) rowf[t] = __expf(acs_s[l0b + t] - aref);
    else if (t - 64 < l0b) colf[t - 64] = __expf(aref - acs_s[t - 64]);
    __syncthreads();

    int lane = t & 63, w = t >> 6;
    int q = lane >> 4, l15 = lane & 15;
    f32x4 acc[4];
#pragma unroll
    for (int j = 0; j < 4; ++j) acc[j] = (f32x4){0.f, 0.f, 0.f, 0.f};

    int nd = lt * 2 + 2;

    auto fill = [&](int kt, int buf) {
        int s0 = kt * 32;
        u16* Wb = Wt[buf]; u16* Pb = Pt[buf];
        if (s0 < l0b) {
            // strictly-below tiles: factored decay = rowf[l] * colf[s]
#pragma unroll
            for (int e = 0; e < 8; ++e) {
                int i = e * 256 + t;
                int sk = i & 31, lr = i >> 5;
                float g = bf2f(G[gbase + (size_t)(l0b + lr) * 256 + s0 + sk]);
                Wb[lr * 38 + sk] = f2bf(g * rowf[lr] * colf[s0 + sk]);
            }
        } else {
            // diagonal tiles: masked direct exp
#pragma unroll
            for (int e = 0; e < 8; ++e) {
                int i = e * 256 + t;
                int sk = i & 31, lr = i >> 5;
                int s = s0 + sk, l = l0b + lr;
                float wv = 0.f;
                if (l >= s)
                    wv = bf2f(G[gbase + (size_t)l * 256 + s]) * __expf(acs_s[l] - acs_s[s]);
                Wb[lr * 38 + sk] = f2bf(wv);
            }
        }
#pragma unroll
        for (int e = 0; e < 8; ++e) {
            int i = e * 256 + t;
            int p = i & 63, sk = i >> 6;
            int s = s0 + sk;
            Pb[p * 38 + sk] = f2bf(bf2f(XCb[(bL + s) * CONVD + h * HD + p]) * dts_s[s]);
        }
    };

    fill(0, 0);
    __syncthreads();
    for (int kt = 0; kt < nd; ++kt) {
        int cur = kt & 1;
        if (kt + 1 < nd) fill(kt + 1, cur ^ 1);
        bf16x8 af = *(const bf16x8*)&Wt[cur][(w * 16 + l15) * 38 + q * 8];
#pragma unroll
        for (int j = 0; j < 4; ++j) {
            bf16x8 bv = *(const bf16x8*)&Pt[cur][(j * 16 + l15) * 38 + q * 8];
            acc[j] = __builtin_amdgcn_mfma_f32_16x16x32_bf16(af, bv, acc[j], 0, 0, 0);
        }
        __syncthreads();
    }
#pragma unroll
    for (int j = 0; j < 4; ++j)
#pragma unroll
        for (int r = 0; r < 4; ++r) {
            size_t idx = (bL + l0b + w * 16 + q * 4 + r) * (size_t)DIN + h * HD + j * 16 + l15;
            Yb[idx] = f2bf(bf2f(Yb[idx]) + acc[j][r]);
        }
}

// ---------------- layernorm * silu(z), in place on Yb ----------------
__global__ __launch_bounds__(256) void k_norm(u16* Yb, const u16* Zb, const void* nw, const int* flagp) {
    int fl = *flagp;
    size_t row = blockIdx.x;
    int t = threadIdx.x;
    size_t base = row * (size_t)DIN;
    float v[8];
#pragma unroll
    for (int k = 0; k < 8; ++k) v[k] = bf2f(Yb[base + k * 256 + t]);
    float s = 0.f;
#pragma unroll
    for (int k = 0; k < 8; ++k) s += v[k];
#pragma unroll
    for (int off = 32; off > 0; off >>= 1) s += __shfl_down(s, off);
    __shared__ float red[4];
    int wid = t >> 6, lid = t & 63;
    if (lid == 0) red[wid] = s;
    __syncthreads();
    float mu = (red[0] + red[1] + red[2] + red[3]) * (1.f / 2048.f);
    float d = 0.f;
#pragma unroll
    for (int k = 0; k < 8; ++k) { float e = v[k] - mu; d += e * e; }
#pragma unroll
    for (int off = 32; off > 0; off >>= 1) d += __shfl_down(d, off);
    __syncthreads();
    if (lid == 0) red[wid] = d;
    __syncthreads();
    float var = (red[0] + red[1] + red[2] + red[3]) * (1.f / 2048.f);
    float rs = rsqrtf(var + 1e-5f);
#pragma unroll
    for (int k = 0; k < 8; ++k) {
        int dcol = k * 256 + t;
        float z = bf2f(Zb[row * DIN + dcol]);
        float sz = z / (1.f + __expf(-z));
        Yb[base + dcol] = f2bf((v[k] - mu) * rs * ldin(nw, dcol, fl) * sz);
    }
}

extern "C" void kernel_launch(void* const* d_in, const int* in_sizes, int n_in,
                              void* d_out, int out_size, void* d_ws, size_t ws_size,
                              hipStream_t stream) {
    const void* u    = d_in[0];
    const void* Win  = d_in[1];
    const void* cw   = d_in[2];
    const void* cb   = d_in[3];
    const void* dtb  = d_in[4];
    const void* alog = d_in[5];
    const void* nw   = d_in[6];
    const void* Wout = d_in[7];

    char* base = (char*)d_ws;
    int*  flag  = (int*)base;
    u16*  Zb    = (u16*)(base + 256);
    u16*  XBCr  = (u16*)(base + 33554688);
    u16*  XCb   = (u16*)(base + 71303424);
    u16*  ST    = (u16*)(base + 109052160);
    u16*  G     = (u16*)(base + 125829376);
    float* DT   = (float*)(base + 130023680);
    float* ACS  = (float*)(base + 131072256);
    float* AL   = (float*)(base + 132120832);
    u16*  DTraw = (u16*)(base + 132124928);
    u16*  Yb    = XBCr;
    u16*  Ub    = (u16*)(base + 71303424);
    u16*  WinT  = (u16*)(base + 88080640);
    u16*  WoutT = (u16*)(base + 109052160);

    k_detect<<<1, 256, 0, stream>>>(u, flag);
    k_cast<<<8192, 256, 0, stream>>>(u, Ub, flag, 2097152);
    k_transpose<<<dim3(140, 32), 256, 0, stream>>>(Win, WinT, 1024, 4384, flag);
    k_gemm_bt<<<dim3(35, 64), 256, 0, stream>>>(Ub, WinT, 1024, 0, Zb, XBCr, DTraw, nullptr, flag);
    k_dtcum<<<1024, 256, 0, stream>>>(DTraw, dtb, alog, flag, DT, ACS, AL);
    k_conv<<<dim3(9, 8192), 256, 0, stream>>>(XBCr, cw, cb, flag, XCb);
    // scores: G = C . B^T per (b,c)
    k_ssd_gemm<<<dim3(2, 2, 32), 256, 0, stream>>>(XCb + DIN + DS, XCb + DIN,
                                                   CONVD, CONVD,
                                                   (size_t)CH * CONVD, (size_t)CH * CONVD,
                                                   0, G, nullptr, nullptr);
    k_states<<<1024, 256, 0, stream>>>(XCb, DT, ACS, AL, ST);
    k_scan<<<64, 256, 0, stream>>>(AL, ST);
    // Y_off: Yb = ea[l] * C @ P_h  (C shared across 32 heads per (b,c))
    k_ssd_gemm<<<dim3(16, 2, 32), 256, 0, stream>>>(XCb + DIN + DS, ST,
                                                    CONVD, 128,
                                                    (size_t)CH * CONVD, (size_t)262144,
                                                    1, nullptr, ACS, Yb);
    // Y_diag: add masked-decay scores @ X'
    k_ydiag<<<4096, 256, 0, stream>>>(XCb, DT, ACS, G, Yb);
    k_transpose<<<dim3(32, 64), 256, 0, stream>>>(Wout, WoutT, 2048, 1024, flag);
    k_norm<<<8192, 256, 0, stream>>>(Yb, Zb, nw, flag);
    k_gemm_bt<<<dim3(8, 64), 256, 0, stream>>>(Yb, WoutT, 2048, 1, nullptr, nullptr, nullptr, d_out, flag);
}

// Round 7
// 672.744 us; speedup vs baseline: 1.0883x; 1.0883x over previous
//
#include <hip/hip_runtime.h>
#include <hip/hip_bf16.h>

// Mamba2 fused block, MI355X. Round 7: Y_off+Y_diag fused into one MFMA GEMM
// (k_yfused): per (bc, m-tile, head-pair) — K=128 state part (DMA-staged) then
// s-tile masked-decay part (G shared across head pair). dt stored chunk-major
// (DTc, ACS-parallel) to kill the 128B-stride scatter.

#define LL 4096
#define DPROJ 4384
#define CONVD 2304
#define DIN 2048
#define NH 32
#define HD 64
#define DS 128
#define CH 256
#define NC 16

typedef unsigned short u16;
typedef unsigned int u32;
typedef __attribute__((ext_vector_type(8))) short bf16x8;
typedef __attribute__((ext_vector_type(4))) float f32x4;

__device__ __forceinline__ float bf2f(u16 v) {
    u32 x = ((u32)v) << 16;
    float f; __builtin_memcpy(&f, &x, 4); return f;
}
__device__ __forceinline__ u16 f2bf(float f) {
    u32 x; __builtin_memcpy(&x, &f, 4);
    u32 r = (x + 0x7fffu + ((x >> 16) & 1u)) >> 16;   // RNE
    return (u16)r;
}
__device__ __forceinline__ float ldin(const void* p, size_t i, int bf) {
    if (bf) return bf2f(((const u16*)p)[i]);
    return ((const float*)p)[i];
}
__device__ __forceinline__ void stout(void* p, size_t i, int bf, float v) {
    if (bf) ((u16*)p)[i] = f2bf(v);
    else    ((float*)p)[i] = v;
}
__device__ __forceinline__ void gll16(const u16* g, u16* l) {
    __builtin_amdgcn_global_load_lds((const u32*)g, (u32*)l, 16, 0, 0);
}

// ---------------- dtype detector ----------------
__global__ void k_detect(const void* u, int* flag) {
    __shared__ int cnt;
    if (threadIdx.x == 0) cnt = 0;
    __syncthreads();
    u16 bits = ((const u16*)u)[2 * threadIdx.x];
    int e = (bits >> 7) & 0xff;
    int ok = (e >= 100 && e <= 141) ? 1 : 0;
    atomicAdd(&cnt, ok);
    __syncthreads();
    if (threadIdx.x == 0) *flag = (cnt > 128) ? 1 : 0;
}

// ---------------- cast to bf16 (identity when input already bf16) ----------------
__global__ void k_cast(const void* src, u16* dst, const int* flagp, int n4) {
    int fl = *flagp;
    size_t i = (size_t)blockIdx.x * 256 + threadIdx.x;
    if (i >= (size_t)n4) return;
    if (fl) {
        ((u32*)dst)[i * 2]     = ((const u32*)src)[i * 2];
        ((u32*)dst)[i * 2 + 1] = ((const u32*)src)[i * 2 + 1];
    } else {
        float4 v = ((const float4*)src)[i];
        dst[i * 4 + 0] = f2bf(v.x); dst[i * 4 + 1] = f2bf(v.y);
        dst[i * 4 + 2] = f2bf(v.z); dst[i * 4 + 3] = f2bf(v.w);
    }
}

// ---------------- transpose + cast: src[R][Cc] -> dst[Cpad][R] bf16, zero-fill ----------------
__global__ __launch_bounds__(256) void k_transpose(const void* src, u16* dst,
                                                   int R, int Cc, const int* flagp) {
    int fl = *flagp;
    __shared__ float tile[32][33];
    int r0 = blockIdx.y * 32, c0 = blockIdx.x * 32;
    int t = threadIdx.x;
    int tr = t >> 5, tc = t & 31;
#pragma unroll
    for (int i = 0; i < 4; ++i) {
        int r = r0 + tr + i * 8, c = c0 + tc;
        float v = 0.f;
        if (c < Cc) v = ldin(src, (size_t)r * Cc + c, fl);
        tile[tr + i * 8][tc] = v;
    }
    __syncthreads();
#pragma unroll
    for (int i = 0; i < 4; ++i) {
        int c = c0 + tr + i * 8, r = r0 + tc;
        dst[(size_t)c * R + r] = f2bf(tile[tc][tr + i * 8]);
    }
}

// ---------------- MFMA GEMM (row stride == K): C = A[M,K] @ Bt[N,K]^T ----------------
__global__ __launch_bounds__(256) void k_gemm_bt(const u16* __restrict__ A, const u16* __restrict__ Bt,
                                                 int K, int mode,
                                                 u16* o0, u16* o1, u16* o2,
                                                 void* outF, const int* flagp) {
    __shared__ __align__(16) u16 sA[4096];
    __shared__ __align__(16) u16 sB[4096];
    int t = threadIdx.x;
    int lane = t & 63, w = t >> 6;
    int wr = w >> 1, wc = w & 1;
    int m0 = blockIdx.y * 128, n0 = blockIdx.x * 128;

    const u16* gA[2]; const u16* gB[2];
    u16* lA[2]; u16* lB[2];
#pragma unroll
    for (int r = 0; r < 2; ++r) {
        int c = w * 128 + r * 64 + lane;
        int m = c >> 2;
        int ks = (c & 3) ^ ((m >> 1) & 3);
        gA[r] = A + (size_t)(m0 + m) * K + ks * 8;
        gB[r] = Bt + (size_t)(n0 + m) * K + ks * 8;
        lA[r] = sA + (size_t)(w * 128 + r * 64) * 8;
        lB[r] = sB + (size_t)(w * 128 + r * 64) * 8;
    }
    int q = lane >> 4, l15 = lane & 15;
    int offA[4], offB[4];
#pragma unroll
    for (int i = 0; i < 4; ++i) {
        int m = wr * 64 + i * 16 + l15;
        offA[i] = (m * 4 + (q ^ ((m >> 1) & 3))) * 8;
        int n = wc * 64 + i * 16 + l15;
        offB[i] = (n * 4 + (q ^ ((n >> 1) & 3))) * 8;
    }
    f32x4 acc[4][4];
#pragma unroll
    for (int i = 0; i < 4; ++i)
#pragma unroll
        for (int j = 0; j < 4; ++j) acc[i][j] = (f32x4){0.f, 0.f, 0.f, 0.f};

    for (int k0 = 0; k0 < K; k0 += 32) {
        gll16(gA[0] + k0, lA[0]);
        gll16(gA[1] + k0, lA[1]);
        gll16(gB[0] + k0, lB[0]);
        gll16(gB[1] + k0, lB[1]);
        __syncthreads();
        bf16x8 af[4], bfv[4];
#pragma unroll
        for (int i = 0; i < 4; ++i) af[i] = *(const bf16x8*)(sA + offA[i]);
#pragma unroll
        for (int i = 0; i < 4; ++i) bfv[i] = *(const bf16x8*)(sB + offB[i]);
#pragma unroll
        for (int i = 0; i < 4; ++i)
#pragma unroll
            for (int j = 0; j < 4; ++j)
                acc[i][j] = __builtin_amdgcn_mfma_f32_16x16x32_bf16(af[i], bfv[j], acc[i][j], 0, 0, 0);
        __syncthreads();
    }

    int fl = (mode == 1) ? *flagp : 0;
#pragma unroll
    for (int i = 0; i < 4; ++i) {
#pragma unroll
        for (int j = 0; j < 4; ++j) {
            int mrow = m0 + wr * 64 + i * 16 + q * 4;
            int n = n0 + wc * 64 + j * 16 + l15;
#pragma unroll
            for (int r = 0; r < 4; ++r) {
                float v = acc[i][j][r];
                size_t m = (size_t)(mrow + r);
                if (mode == 0) {
                    if (n < DIN) o0[m * DIN + n] = f2bf(v);
                    else if (n < DIN + CONVD) o1[m * CONVD + (n - DIN)] = f2bf(v);
                    else if (n < DPROJ) o2[m * NH + (n - DIN - CONVD)] = f2bf(v);
                } else {
                    stout(outF, m * 1024 + n, fl, v);
                }
            }
        }
    }
}

// ---------------- scores: G[bc][l][s] = C[l]·B[s], K=128, strided batch ----------------
__global__ __launch_bounds__(256) void k_scores(const u16* __restrict__ XCb, u16* G) {
    int bc = blockIdx.z;
    const u16* A  = XCb + (size_t)bc * CH * CONVD + DIN + DS;
    const u16* Bt = XCb + (size_t)bc * CH * CONVD + DIN;
    __shared__ __align__(16) u16 sA[4096];
    __shared__ __align__(16) u16 sB[4096];
    int t = threadIdx.x;
    int lane = t & 63, w = t >> 6;
    int wr = w >> 1, wc = w & 1;
    int m0 = blockIdx.y * 128, n0 = blockIdx.x * 128;

    const u16* gA[2]; const u16* gB[2];
    u16* lA[2]; u16* lB[2];
#pragma unroll
    for (int r = 0; r < 2; ++r) {
        int c = w * 128 + r * 64 + lane;
        int m = c >> 2;
        int ks = (c & 3) ^ ((m >> 1) & 3);
        gA[r] = A + (size_t)(m0 + m) * CONVD + ks * 8;
        gB[r] = Bt + (size_t)(n0 + m) * CONVD + ks * 8;
        lA[r] = sA + (size_t)(w * 128 + r * 64) * 8;
        lB[r] = sB + (size_t)(w * 128 + r * 64) * 8;
    }
    int q = lane >> 4, l15 = lane & 15;
    int offA[4], offB[4];
#pragma unroll
    for (int i = 0; i < 4; ++i) {
        int m = wr * 64 + i * 16 + l15;
        offA[i] = (m * 4 + (q ^ ((m >> 1) & 3))) * 8;
        int n = wc * 64 + i * 16 + l15;
        offB[i] = (n * 4 + (q ^ ((n >> 1) & 3))) * 8;
    }
    f32x4 acc[4][4];
#pragma unroll
    for (int i = 0; i < 4; ++i)
#pragma unroll
        for (int j = 0; j < 4; ++j) acc[i][j] = (f32x4){0.f, 0.f, 0.f, 0.f};

    for (int k0 = 0; k0 < 128; k0 += 32) {
        gll16(gA[0] + k0, lA[0]);
        gll16(gA[1] + k0, lA[1]);
        gll16(gB[0] + k0, lB[0]);
        gll16(gB[1] + k0, lB[1]);
        __syncthreads();
        bf16x8 af[4], bfv[4];
#pragma unroll
        for (int i = 0; i < 4; ++i) af[i] = *(const bf16x8*)(sA + offA[i]);
#pragma unroll
        for (int i = 0; i < 4; ++i) bfv[i] = *(const bf16x8*)(sB + offB[i]);
#pragma unroll
        for (int i = 0; i < 4; ++i)
#pragma unroll
            for (int j = 0; j < 4; ++j)
                acc[i][j] = __builtin_amdgcn_mfma_f32_16x16x32_bf16(af[i], bfv[j], acc[i][j], 0, 0, 0);
        __syncthreads();
    }
    size_t gb = (size_t)bc * 65536;
#pragma unroll
    for (int i = 0; i < 4; ++i) {
#pragma unroll
        for (int j = 0; j < 4; ++j) {
            int mrow = m0 + wr * 64 + i * 16 + q * 4;
            int n = n0 + wc * 64 + j * 16 + l15;
#pragma unroll
            for (int r = 0; r < 4; ++r)
                G[gb + (size_t)(mrow + r) * 256 + n] = f2bf(acc[i][j][r]);
        }
    }
}

// ---------------- dt softplus + per-chunk cumsum of dA (DTc chunk-major) ----------------
__global__ __launch_bounds__(256) void k_dtcum(const u16* DTraw, const void* dtb, const void* alog,
                                               const int* flagp, float* DTc, float* ACS, float* AL) {
    int fl = *flagp;
    int bid = blockIdx.x;                 // (b*16+c)*32+h
    int b = bid >> 9, c = (bid >> 5) & 15, h = bid & 31;
    int t = threadIdx.x;
    size_t bl = (size_t)b * LL + c * CH + t;
    float v = bf2f(DTraw[bl * NH + h]) + ldin(dtb, h, fl);
    float sp = (v > 20.f) ? v : log1pf(__expf(v));
    DTc[(size_t)bid * CH + t] = sp;
    float da = -__expf(ldin(alog, h, fl)) * sp;
    __shared__ float sc[256];
    sc[t] = da;
    __syncthreads();
    for (int off = 1; off < 256; off <<= 1) {
        float add = (t >= off) ? sc[t - off] : 0.f;
        __syncthreads();
        sc[t] += add;
        __syncthreads();
    }
    ACS[(size_t)bid * CH + t] = sc[t];
    if (t == 255) AL[bid] = sc[255];
}

// ---------------- causal depthwise conv (width 4) + silu ----------------
__global__ void k_conv(const u16* XBCr, const void* cw, const void* cb, const int* flagp, u16* XCb) {
    int fl = *flagp;
    int ch = blockIdx.x * 256 + threadIdx.x;   // 0..2303 (grid.x = 9)
    size_t bl = blockIdx.y;                    // 0..8191
    int l = (int)(bl & 4095);
    float acc = ldin(cb, ch, fl);
#pragma unroll
    for (int j = 0; j < 4; ++j) {
        int ls = l + j - 3;
        if (ls >= 0)
            acc += bf2f(XBCr[(bl - l + ls) * CONVD + ch]) * ldin(cw, (size_t)ch * 4 + j, fl);
    }
    acc = acc / (1.f + __expf(-acc));
    XCb[bl * CONVD + ch] = f2bf(acc);
}

// ---------------- per-chunk states via MFMA: STt[p][n] = sum_l X[l,p]*wl[l] * B[l,n] ----------------
__global__ __launch_bounds__(256) void k_states(const u16* XCb, const float* DTc, const float* ACS,
                                                const float* AL, u16* STt) {
    int bid = blockIdx.x;            // (b*16+c)*32+h
    int b = bid >> 9, c = (bid >> 5) & 15, h = bid & 31;
    int t = threadIdx.x;
    size_t bL = (size_t)b * LL + c * CH;
    __shared__ float wl[256];
    __shared__ __align__(16) u16 Wt[128 * 38];   // B^T: [n][lk]
    __shared__ __align__(16) u16 Pt[64 * 38];    // X^T*wl: [p][lk]
    float al = AL[bid];
    wl[t] = __expf(al - ACS[(size_t)bid * CH + t]) * DTc[(size_t)bid * CH + t];
    __syncthreads();

    int lane = t & 63, w = t >> 6;
    int q = lane >> 4, l15 = lane & 15;
    f32x4 acc[8];
#pragma unroll
    for (int j = 0; j < 8; ++j) acc[j] = (f32x4){0.f, 0.f, 0.f, 0.f};

    for (int kt = 0; kt < 8; ++kt) {
        int l0 = kt * 32;
        if (kt) __syncthreads();
#pragma unroll
        for (int e = 0; e < 16; ++e) {
            int i = e * 256 + t;
            int n = i & 127, lk = i >> 7;
            Wt[n * 38 + lk] = XCb[(bL + l0 + lk) * CONVD + DIN + n];
        }
#pragma unroll
        for (int e = 0; e < 8; ++e) {
            int i = e * 256 + t;
            int p = i & 63, lk = i >> 6;
            float v = bf2f(XCb[(bL + l0 + lk) * CONVD + h * HD + p]) * wl[l0 + lk];
            Pt[p * 38 + lk] = f2bf(v);
        }
        __syncthreads();
        bf16x8 af = *(const bf16x8*)&Pt[(w * 16 + l15) * 38 + q * 8];
#pragma unroll
        for (int j = 0; j < 8; ++j) {
            bf16x8 bv = *(const bf16x8*)&Wt[(j * 16 + l15) * 38 + q * 8];
            acc[j] = __builtin_amdgcn_mfma_f32_16x16x32_bf16(af, bv, acc[j], 0, 0, 0);
        }
    }
    size_t sbase = (size_t)bid * 8192;
#pragma unroll
    for (int j = 0; j < 8; ++j)
#pragma unroll
        for (int r = 0; r < 4; ++r)
            STt[sbase + (size_t)(w * 16 + q * 4 + r) * 128 + j * 16 + l15] = f2bf(acc[j][r]);
}

// ---------------- inter-chunk scan (in place; f32 carry; layout-agnostic) ----------------
__global__ __launch_bounds__(256) void k_scan(const float* AL, u16* ST) {
    int bid = blockIdx.x;  // b*32+h
    int b = bid >> 5, h = bid & 31;
    int t = threadIdx.x;
    float Pv[32];
#pragma unroll
    for (int k = 0; k < 32; ++k) Pv[k] = 0.f;
    for (int c = 0; c < NC; ++c) {
        int bch = (b * NC + c) * NH + h;
        float ga = __expf(AL[bch]);
        size_t base = (size_t)bch * 8192;
#pragma unroll
        for (int k = 0; k < 32; ++k) {
            size_t idx = base + (size_t)k * 256 + t;
            float s = bf2f(ST[idx]);
            ST[idx] = f2bf(Pv[k]);
            Pv[k] = ga * Pv[k] + s;
        }
    }
}

// ---------------- fused Y = ea[l]*(C@P_h) + (G.*decay.*mask)@(X*dt) ----------------
// grid (16, 2, 32): x = head-pair (n0=x*128), y = m-tile (m0=y*128), z = bc
__global__ __launch_bounds__(256) void k_yfused(const u16* __restrict__ XCb, const float* DTc,
                                                const float* ACS, const u16* __restrict__ G,
                                                const u16* __restrict__ STt, u16* Yb) {
    int bc = blockIdx.z;
    int b = bc >> 4, c = bc & 15;
    int m0 = blockIdx.y * 128;
    int hq = blockIdx.x * 2;
    int t = threadIdx.x;
    size_t bL = (size_t)b * LL + c * CH;
    size_t gbase = (size_t)bc * 65536;

    __shared__ __align__(16) char smem[35328];
    u16* sA  = (u16*)smem;                 // off staging A (8192 B)
    u16* sB  = (u16*)(smem + 8192);        // off staging B (8192 B)
    u16* Wt0 = (u16*)smem;                 // diag A head0 (128x38)
    u16* Wt1 = (u16*)(smem + 9728);        // diag A head1
    u16* Pt0 = (u16*)(smem + 19456);       // diag B head0 (64x38)
    u16* Pt1 = (u16*)(smem + 24320);       // diag B head1
    float* acs  = (float*)(smem + 29184);  // [2][256]
    float* dts  = (float*)(smem + 31232);  // [2][256]
    float* rowf = (float*)(smem + 33280);  // [2][128]
    float* colf = (float*)(smem + 34304);  // [2][128]

    // phase 0: per-head scalars
#pragma unroll
    for (int hh = 0; hh < 2; ++hh) {
        size_t bid = (size_t)bc * 32 + hq + hh;
        acs[hh * 256 + t] = ACS[bid * 256 + t];
        dts[hh * 256 + t] = DTc[bid * 256 + t];
    }
    __syncthreads();
    {
        int hh = t >> 7, lr = t & 127;
        float aref = acs[hh * 256 + m0];
        rowf[hh * 128 + lr] = __expf(acs[hh * 256 + m0 + lr] - aref);
        colf[hh * 128 + lr] = (lr < m0) ? __expf(aref - acs[hh * 256 + lr]) : 0.f;
    }
    __syncthreads();

    int lane = t & 63, w = t >> 6;
    int wr = w >> 1, wc = w & 1;
    int q = lane >> 4, l15 = lane & 15;

    // phase 1: off part, K=128 (C rows vs STt rows), DMA-staged
    const u16* A  = XCb + (size_t)bc * CH * CONVD + DIN + DS;
    const u16* Bt = STt + (size_t)bc * 262144;
    int n0 = blockIdx.x * 128;
    const u16* gA[2]; const u16* gB[2];
    u16* lA[2]; u16* lB[2];
#pragma unroll
    for (int r = 0; r < 2; ++r) {
        int cc = w * 128 + r * 64 + lane;
        int m = cc >> 2;
        int ks = (cc & 3) ^ ((m >> 1) & 3);
        gA[r] = A + (size_t)(m0 + m) * CONVD + ks * 8;
        gB[r] = Bt + (size_t)(n0 + m) * 128 + ks * 8;
        lA[r] = sA + (size_t)(w * 128 + r * 64) * 8;
        lB[r] = sB + (size_t)(w * 128 + r * 64) * 8;
    }
    int offA[4], offB[4];
#pragma unroll
    for (int i = 0; i < 4; ++i) {
        int m = wr * 64 + i * 16 + l15;
        offA[i] = (m * 4 + (q ^ ((m >> 1) & 3))) * 8;
        int n = wc * 64 + i * 16 + l15;
        offB[i] = (n * 4 + (q ^ ((n >> 1) & 3))) * 8;
    }
    f32x4 acc[4][4];
#pragma unroll
    for (int i = 0; i < 4; ++i)
#pragma unroll
        for (int j = 0; j < 4; ++j) acc[i][j] = (f32x4){0.f, 0.f, 0.f, 0.f};

    for (int k0 = 0; k0 < 128; k0 += 32) {
        gll16(gA[0] + k0, lA[0]);
        gll16(gA[1] + k0, lA[1]);
        gll16(gB[0] + k0, lB[0]);
        gll16(gB[1] + k0, lB[1]);
        __syncthreads();
        bf16x8 af[4], bfv[4];
#pragma unroll
        for (int i = 0; i < 4; ++i) af[i] = *(const bf16x8*)(sA + offA[i]);
#pragma unroll
        for (int i = 0; i < 4; ++i) bfv[i] = *(const bf16x8*)(sB + offB[i]);
#pragma unroll
        for (int i = 0; i < 4; ++i)
#pragma unroll
            for (int j = 0; j < 4; ++j)
                acc[i][j] = __builtin_amdgcn_mfma_f32_16x16x32_bf16(af[i], bfv[j], acc[i][j], 0, 0, 0);
        __syncthreads();
    }

    // scale off part by ea[l] (head = wc)
    const float* acsh = acs + wc * 256;
#pragma unroll
    for (int i = 0; i < 4; ++i) {
        int lb = m0 + wr * 64 + i * 16 + q * 4;
        float e0 = __expf(acsh[lb]), e1 = __expf(acsh[lb + 1]);
        float e2 = __expf(acsh[lb + 2]), e3 = __expf(acsh[lb + 3]);
#pragma unroll
        for (int j = 0; j < 4; ++j) {
            acc[i][j][0] *= e0; acc[i][j][1] *= e1;
            acc[i][j][2] *= e2; acc[i][j][3] *= e3;
        }
    }

    // phase 2: diag part over s-tiles
    int smax = (m0 == 0) ? 4 : 8;
    for (int st = 0; st < smax; ++st) {
        int s0 = st * 32;
        if (s0 + 32 <= m0) {
            // strictly below: factored decay
#pragma unroll
            for (int e = 0; e < 16; ++e) {
                int i = e * 256 + t;
                int sk = i & 31, lr = i >> 5;
                float g = bf2f(G[gbase + (size_t)(m0 + lr) * 256 + s0 + sk]);
                Wt0[lr * 38 + sk] = f2bf(g * rowf[lr] * colf[s0 + sk]);
                Wt1[lr * 38 + sk] = f2bf(g * rowf[128 + lr] * colf[128 + s0 + sk]);
            }
        } else {
            // diagonal band: masked direct exp (exponent <= 0, safe)
#pragma unroll
            for (int e = 0; e < 16; ++e) {
                int i = e * 256 + t;
                int sk = i & 31, lr = i >> 5;
                int l = m0 + lr, s = s0 + sk;
                float w0 = 0.f, w1 = 0.f;
                if (l >= s) {
                    float g = bf2f(G[gbase + (size_t)l * 256 + s]);
                    w0 = g * __expf(acs[l] - acs[s]);
                    w1 = g * __expf(acs[256 + l] - acs[256 + s]);
                }
                Wt0[lr * 38 + sk] = f2bf(w0);
                Wt1[lr * 38 + sk] = f2bf(w1);
            }
        }
#pragma unroll
        for (int e = 0; e < 16; ++e) {
            int i = e * 256 + t;
            int hh = i >> 11, jj = i & 2047;
            int p = jj & 63, sk = jj >> 6;
            int s = s0 + sk;
            float v = bf2f(XCb[(bL + s) * CONVD + (hq + hh) * 64 + p]) * dts[hh * 256 + s];
            (hh ? Pt1 : Pt0)[p * 38 + sk] = f2bf(v);
        }
        __syncthreads();
        u16* Wth = wc ? Wt1 : Wt0;
        u16* Pth = wc ? Pt1 : Pt0;
        bf16x8 af[4], bfv[4];
#pragma unroll
        for (int i = 0; i < 4; ++i)
            af[i] = *(const bf16x8*)&Wth[(wr * 64 + i * 16 + l15) * 38 + q * 8];
#pragma unroll
        for (int j = 0; j < 4; ++j)
            bfv[j] = *(const bf16x8*)&Pth[(j * 16 + l15) * 38 + q * 8];
#pragma unroll
        for (int i = 0; i < 4; ++i)
#pragma unroll
            for (int j = 0; j < 4; ++j)
                acc[i][j] = __builtin_amdgcn_mfma_f32_16x16x32_bf16(af[i], bfv[j], acc[i][j], 0, 0, 0);
        __syncthreads();
    }

    // epilogue: plain store
#pragma unroll
    for (int i = 0; i < 4; ++i) {
        int l = m0 + wr * 64 + i * 16 + q * 4;
#pragma unroll
        for (int j = 0; j < 4; ++j) {
            int col = (hq + wc) * 64 + j * 16 + l15;
#pragma unroll
            for (int r = 0; r < 4; ++r)
                Yb[(bL + l + r) * (size_t)DIN + col] = f2bf(acc[i][j][r]);
        }
    }
}

// ---------------- layernorm * silu(z), in place on Yb ----------------
__global__ __launch_bounds__(256) void k_norm(u16* Yb, const u16* Zb, const void* nw, const int* flagp) {
    int fl = *flagp;
    size_t row = blockIdx.x;
    int t = threadIdx.x;
    size_t base = row * (size_t)DIN;
    float v[8];
#pragma unroll
    for (int k = 0; k < 8; ++k) v[k] = bf2f(Yb[base + k * 256 + t]);
    float s = 0.f;
#pragma unroll
    for (int k = 0; k < 8; ++k) s += v[k];
#pragma unroll
    for (int off = 32; off > 0; off >>= 1) s += __shfl_down(s, off);
    __shared__ float red[4];
    int wid = t >> 6, lid = t & 63;
    if (lid == 0) red[wid] = s;
    __syncthreads();
    float mu = (red[0] + red[1] + red[2] + red[3]) * (1.f / 2048.f);
    float d = 0.f;
#pragma unroll
    for (int k = 0; k < 8; ++k) { float e = v[k] - mu; d += e * e; }
#pragma unroll
    for (int off = 32; off > 0; off >>= 1) d += __shfl_down(d, off);
    __syncthreads();
    if (lid == 0) red[wid] = d;
    __syncthreads();
    float var = (red[0] + red[1] + red[2] + red[3]) * (1.f / 2048.f);
    float rs = rsqrtf(var + 1e-5f);
#pragma unroll
    for (int k = 0; k < 8; ++k) {
        int dcol = k * 256 + t;
        float z = bf2f(Zb[row * DIN + dcol]);
        float sz = z / (1.f + __expf(-z));
        Yb[base + dcol] = f2bf((v[k] - mu) * rs * ldin(nw, dcol, fl) * sz);
    }
}

extern "C" void kernel_launch(void* const* d_in, const int* in_sizes, int n_in,
                              void* d_out, int out_size, void* d_ws, size_t ws_size,
                              hipStream_t stream) {
    const void* u    = d_in[0];
    const void* Win  = d_in[1];
    const void* cw   = d_in[2];
    const void* cb   = d_in[3];
    const void* dtb  = d_in[4];
    const void* alog = d_in[5];
    const void* nw   = d_in[6];
    const void* Wout = d_in[7];

    char* base = (char*)d_ws;
    int*  flag  = (int*)base;
    u16*  Zb    = (u16*)(base + 256);
    u16*  XBCr  = (u16*)(base + 33554688);
    u16*  XCb   = (u16*)(base + 71303424);
    u16*  ST    = (u16*)(base + 109052160);
    u16*  G     = (u16*)(base + 125829376);
    float* DTc  = (float*)(base + 130023680);
    float* ACS  = (float*)(base + 131072256);
    float* AL   = (float*)(base + 132120832);
    u16*  DTraw = (u16*)(base + 132124928);
    u16*  Yb    = XBCr;
    u16*  Ub    = (u16*)(base + 71303424);
    u16*  WinT  = (u16*)(base + 88080640);
    u16*  WoutT = (u16*)(base + 109052160);

    k_detect<<<1, 256, 0, stream>>>(u, flag);
    k_cast<<<8192, 256, 0, stream>>>(u, Ub, flag, 2097152);
    k_transpose<<<dim3(140, 32), 256, 0, stream>>>(Win, WinT, 1024, 4384, flag);
    k_gemm_bt<<<dim3(35, 64), 256, 0, stream>>>(Ub, WinT, 1024, 0, Zb, XBCr, DTraw, nullptr, flag);
    k_dtcum<<<1024, 256, 0, stream>>>(DTraw, dtb, alog, flag, DTc, ACS, AL);
    k_conv<<<dim3(9, 8192), 256, 0, stream>>>(XBCr, cw, cb, flag, XCb);
    k_scores<<<dim3(2, 2, 32), 256, 0, stream>>>(XCb, G);
    k_states<<<1024, 256, 0, stream>>>(XCb, DTc, ACS, AL, ST);
    k_scan<<<64, 256, 0, stream>>>(AL, ST);
    // fused Y (off + diag)
    k_yfused<<<dim3(16, 2, 32), 256, 0, stream>>>(XCb, DTc, ACS, G, ST, Yb);
    k_transpose<<<dim3(32, 64), 256, 0, stream>>>(Wout, WoutT, 2048, 1024, flag);
    k_norm<<<8192, 256, 0, stream>>>(Yb, Zb, nw, flag);
    k_gemm_bt<<<dim3(8, 64), 256, 0, stream>>>(Yb, WoutT, 2048, 1, nullptr, nullptr, nullptr, d_out, flag);
}